// Round 3
// baseline (362.890 us; speedup 1.0000x reference)
//
#include <hip/hip_runtime.h>

// DGPE ODE RHS, 6-point periodic stencil on 192^3 lattice, fp32.
// R3: float4 along z (4 sites/thread) + XCD slab swizzle.
// NO nontemporal ops — nt (L2-bypass) stores raced with the harness's
// poison memset dirty lines in L2 and clobbered d_out post-timing (R2 fail).

#define LDIM 192
#define LSQ  (LDIM * LDIM)          // 36864
#define NTOT (LDIM * LDIM * LDIM)   // 7077888
#define NQ   (NTOT / 4)             // 1769472 threads (4 sites each)
#define NBLK (NQ / 256)             // 6912 blocks
#define XCDS 8
#define BPX  (NBLK / XCDS)          // 864 blocks per XCD slab (24 x-planes)

typedef float f4 __attribute__((ext_vector_type(4)));

__global__ __launch_bounds__(256) void dgpe_kernel(
    const float* __restrict__ y,
    const float* __restrict__ Jarr,
    const float* __restrict__ aniso,
    const float* __restrict__ gam,
    const float* __restrict__ hdx,
    const float* __restrict__ hdy,
    const float* __restrict__ beta,
    const float* __restrict__ edis,
    float* __restrict__ out)
{
    // XCD slab swizzle: physical block pb lands on XCD pb%8 (round-robin
    // dispatch); give XCD k the contiguous logical slab [k*BPX,(k+1)*BPX)
    // so x/y-neighbor planes stay resident in that XCD's 4 MiB L2.
    const int pb = blockIdx.x;
    const int lb = (pb & (XCDS - 1)) * BPX + (pb >> 3);
    const int t  = lb * 256 + threadIdx.x;
    const int i  = t * 4;                       // base site index (16B-aligned)

    // decompose: t = (a*192 + b)*48 + q, c4 = 4*q
    const unsigned ut  = (unsigned)t;
    const unsigned r   = ut / 48u;              // a*192 + b
    const unsigned c4  = (ut - r * 48u) * 4u;   // z base within row
    const unsigned a   = r / 192u;
    const unsigned b   = r - a * 192u;

    // periodic neighbor base indices (all float4-aligned)
    const int xm = (a == 0)        ? i + (LDIM - 1) * LSQ  : i - LSQ;
    const int xp = (a == LDIM - 1) ? i - (LDIM - 1) * LSQ  : i + LSQ;
    const int ym = (b == 0)        ? i + (LDIM - 1) * LDIM : i - LDIM;
    const int yp = (b == LDIM - 1) ? i - (LDIM - 1) * LDIM : i + LDIM;
    const int rowbase = i - (int)c4;            // a*LSQ + b*LDIM
    const int zmi = (c4 == 0)   ? rowbase + (LDIM - 1) : i - 1;
    const int zpi = (c4 == 188) ? rowbase              : i + 4;

    const float* __restrict__ x = y;
    const float* __restrict__ p = y + NTOT;

    const f4 xc  = *(const f4*)(x + i);
    const f4 xxm = *(const f4*)(x + xm);
    const f4 xxp = *(const f4*)(x + xp);
    const f4 xym = *(const f4*)(x + ym);
    const f4 xyp = *(const f4*)(x + yp);
    const float xzm = x[zmi];
    const float xzp = x[zpi];

    const f4 pc  = *(const f4*)(p + i);
    const f4 pxm = *(const f4*)(p + xm);
    const f4 pxp = *(const f4*)(p + xp);
    const f4 pym = *(const f4*)(p + ym);
    const f4 pyp = *(const f4*)(p + yp);
    const float pzm = p[zmi];
    const float pzp = p[zpi];

    const f4 J  = *(const f4*)(Jarr  + i);
    const f4 an = *(const f4*)(aniso + i);
    const f4 g  = *(const f4*)(gam   + i);
    const f4 hx = *(const f4*)(hdx   + i);
    const f4 hy = *(const f4*)(hdy   + i);
    const f4 bt = *(const f4*)(beta  + i);
    const f4 ed = *(const f4*)(edis  + i);

    // z-direction sums from registers
    f4 xz, pz;
    xz.x = xzm  + xc.y;  xz.y = xc.x + xc.z;
    xz.z = xc.y + xc.w;  xz.w = xc.z + xzp;
    pz.x = pzm  + pc.y;  pz.y = pc.x + pc.z;
    pz.z = pc.y + pc.w;  pz.w = pc.z + pzp;

    const f4 xL = J * ((xxm + xxp + xym + xyp) + an * xz);
    const f4 yL = J * ((pxm + pxp + pym + pyp) + an * pz);

    const f4 r2    = xc * xc + pc * pc;
    const f4 cross = xL * pc - yL * xc;

    const f4 dx =  g * pc * cross + ed * pc - yL + hy + bt * r2 * pc;
    const f4 dp = -(g * xc * cross) - ed * xc + xL - hx - bt * r2 * xc;

    *(f4*)(out + i)        = dx;
    *(f4*)(out + NTOT + i) = dp;
}

extern "C" void kernel_launch(void* const* d_in, const int* in_sizes, int n_in,
                              void* d_out, int out_size, void* d_ws, size_t ws_size,
                              hipStream_t stream) {
    const float* y_    = (const float*)d_in[1];
    const float* Jarr  = (const float*)d_in[2];
    const float* aniso = (const float*)d_in[3];
    const float* gam   = (const float*)d_in[4];
    const float* hdx   = (const float*)d_in[5];
    const float* hdy   = (const float*)d_in[6];
    const float* beta  = (const float*)d_in[7];
    const float* edis  = (const float*)d_in[8];
    float* out = (float*)d_out;

    dgpe_kernel<<<NBLK, 256, 0, stream>>>(y_, Jarr, aniso, gam, hdx, hdy,
                                          beta, edis, out);
}